// Round 4
// baseline (489.740 us; speedup 1.0000x reference)
//
#include <hip/hip_runtime.h>
#include <hip/hip_bf16.h>

typedef unsigned short u16;
typedef __attribute__((ext_vector_type(8))) short short8;
typedef __attribute__((ext_vector_type(4))) short short4v;
typedef __attribute__((ext_vector_type(4))) float floatx4;

constexpr int SEQ = 4096;
constexpr int DM  = 2048;
constexpr int NH  = 16;
constexpr int HD  = 128;

__device__ inline u16 f2b(float f) {
    __hip_bfloat16 h = __float2bfloat16(f);
    return *reinterpret_cast<u16*>(&h);
}
__device__ inline float b2f(u16 u) {
    __hip_bfloat16 h = *reinterpret_cast<__hip_bfloat16*>(&u);
    return __bfloat162float(h);
}

__device__ __forceinline__ void async_copy16(const u16* g, u16* lds_base) {
    __builtin_amdgcn_global_load_lds(
        (const __attribute__((address_space(1))) unsigned int*)g,
        (__attribute__((address_space(3))) unsigned int*)lds_base,
        16, 0, 0);
}

// ---------------------------------------------------------------------------
__global__ void detect_dtype(const u16* __restrict__ X, int* __restrict__ flag) {
    __shared__ int cnt;
    if (threadIdx.x == 0) cnt = 0;
    __syncthreads();
    int local = 0;
    for (int i = threadIdx.x; i < 4096; i += 256) {
        int e = (X[i] >> 7) & 0xFF;
        if (e >= 0x3C && e <= 0x8D) local++;
    }
    atomicAdd(&cnt, local);
    __syncthreads();
    if (threadIdx.x == 0) *flag = (cnt >= 3890) ? 1 : 0;
}

// One launch converts all 9 float tensors (bf16 passthrough or fp32 round).
struct ConvArgs {
    const void* src[9];
    unsigned long long dstoff[9];  // u16-element offset from base
    int n[9];
};
__global__ void convert_all(ConvArgs a, u16* __restrict__ base,
                            const int* __restrict__ flag) {
    const int t = blockIdx.y;
    const int n = a.n[t];
    const int i = (blockIdx.x * blockDim.x + threadIdx.x) * 8;
    if (i >= n) return;
    u16* out = base + a.dstoff[t];
    if (*flag) {
        *(short8*)&out[i] = *(const short8*)&((const u16*)a.src[t])[i];
    } else {
        const float* p = (const float*)a.src[t];
        u16 tmp[8];
#pragma unroll
        for (int j = 0; j < 8; j++) tmp[j] = f2b(p[i + j]);
        *(short8*)&out[i] = *(const short8*)tmp;
    }
}

// ---------------------------------------------------------------------------
// 256x256 8-phase GEMM core — faithful m201-class schedule in plain HIP.
//   BM=BN=256, BK=64, 512 thr = 8 waves (2M x 4N), wave out 128x64,
//   16 MFMA per phase (one C-quadrant x K=64), 4 phases per K-tile.
//   LDS: 2 parity bufs x (A 32KB + B 32KB) = 128 KiB.
//   Phase = {4/12 ds_read (next subtile) || stage -> barrier ->
//            counted lgkmcnt -> sched_barrier(0) -> setprio(1) 16 MFMA
//            setprio(0) -> barrier}.
//   Read map: t.ph3 reads B(t+1) frags (8) + A(t+1) q0 (4)  [12-read phase];
//             t.ph0/1/2 read A(t) q1/q2/q3 (4 each).
//   Stage map (derived from 2-barrier visibility rule):
//             t.ph0: A(t+1) x4   (A(t-1) slot free since (t-1).ph2+barrier)
//             t.ph1: B(t+2) h0   (B(t)  slot free since t.ph0 closing barrier)
//             t.ph2: B(t+2) h1
//   vmcnt ledger (per-wave FIFO): at end t.ph2 outstanding =
//     {B(t+1)x4 [older], A(t+1)x4, B(t+2)x4 [newest]} -> vmcnt(4) forces
//     A(t+1)+B(t+1) landed, leaves B(t+2) in flight. ONE wait per K-tile.
//   B frag registers double-buffered via 2-tile-unrolled loop (static idx).
// ---------------------------------------------------------------------------
__device__ __forceinline__ void gemm256_core(
    const u16* __restrict__ A, const u16* __restrict__ W,
    int m0, int n0, floatx4 (&acc)[8][4])
{
    __shared__ __align__(16) u16 As[2][16384];   // 256 x 64 per parity
    __shared__ __align__(16) u16 Bs[2][16384];   // 256 x 64 per parity
    constexpr int K  = DM;
    constexpr int NT = K / 64;   // 32 (even)

    const int tid  = threadIdx.x;
    const int lane = tid & 63;
    const int w    = tid >> 6;            // 0..7
    const int qm   = lane & 15;
    const int quad = lane >> 4;
    const int wm   = (w >> 2) * 128;      // wave rows: 0 / 128
    const int wn   = (w & 3) * 64;        // wave cols: 0/64/128/192

    // staging: thread t covers LDS linear [slot*8192B + tid*16B, +16B)
    // source pre-swizzle: global granule = (t&7) ^ (row&7)
    const int srow = tid >> 3;                       // 0..63
    const int scol = ((tid & 7) ^ (srow & 7)) * 8;   // elems

    // frag-read swizzle: physical granule = (kh*4+quad) ^ (row&7); row&7==qm&7
    const int fo0 = (quad ^ (qm & 7)) * 8;
    const int fo1 = fo0 ^ 32;

    const u16* Ag = A + (size_t)(m0 + srow) * K + scol;
    const u16* Wg = W + (size_t)(n0 + srow) * K + scol;

#define STG_A_ALL(par, k0) {                                                    \
    async_copy16(Ag + (size_t)0 * 64 * K + (k0), &As[par][0 * 4096 + w * 512]); \
    async_copy16(Ag + (size_t)1 * 64 * K + (k0), &As[par][1 * 4096 + w * 512]); \
    async_copy16(Ag + (size_t)2 * 64 * K + (k0), &As[par][2 * 4096 + w * 512]); \
    async_copy16(Ag + (size_t)3 * 64 * K + (k0), &As[par][3 * 4096 + w * 512]); }
#define STG_B_H(h, par, k0) {                                                   \
    async_copy16(Wg + (size_t)(2*(h)) * 64 * K + (k0),                          \
                 &Bs[par][(2*(h)) * 4096 + w * 512]);                           \
    async_copy16(Wg + (size_t)(2*(h)+1) * 64 * K + (k0),                        \
                 &Bs[par][(2*(h)+1) * 4096 + w * 512]); }

#define RD_AQ(dst, Abase, q) {                                                  \
    dst[0][0] = *(const short8*)&Abase[(wm + (2*(q)) * 16 + qm) * 64 + fo0];    \
    dst[0][1] = *(const short8*)&Abase[(wm + (2*(q)) * 16 + qm) * 64 + fo1];    \
    dst[1][0] = *(const short8*)&Abase[(wm + (2*(q)+1) * 16 + qm) * 64 + fo0];  \
    dst[1][1] = *(const short8*)&Abase[(wm + (2*(q)+1) * 16 + qm) * 64 + fo1]; }

#define RD_B(dst, Bbase) {                                                      \
    _Pragma("unroll")                                                           \
    for (int nt = 0; nt < 4; ++nt) {                                            \
        dst[nt][0] = *(const short8*)&Bbase[(wn + nt * 16 + qm) * 64 + fo0];    \
        dst[nt][1] = *(const short8*)&Bbase[(wn + nt * 16 + qm) * 64 + fo1];    \
    } }

#define MFMA_Q(q, aR, bR) {                                                     \
    __builtin_amdgcn_s_setprio(1);                                              \
    _Pragma("unroll")                                                           \
    for (int nt = 0; nt < 4; ++nt) {                                            \
        acc[2*(q)][nt]   = __builtin_amdgcn_mfma_f32_16x16x32_bf16(aR[0][0], bR[nt][0], acc[2*(q)][nt],   0, 0, 0); \
        acc[2*(q)][nt]   = __builtin_amdgcn_mfma_f32_16x16x32_bf16(aR[0][1], bR[nt][1], acc[2*(q)][nt],   0, 0, 0); \
        acc[2*(q)+1][nt] = __builtin_amdgcn_mfma_f32_16x16x32_bf16(aR[1][0], bR[nt][0], acc[2*(q)+1][nt], 0, 0, 0); \
        acc[2*(q)+1][nt] = __builtin_amdgcn_mfma_f32_16x16x32_bf16(aR[1][1], bR[nt][1], acc[2*(q)+1][nt], 0, 0, 0); \
    }                                                                           \
    __builtin_amdgcn_s_setprio(0); }

// One K-tile = 4 phases. BCUR = B frags of tile T; BNXT filled at ph3.
#define TILE_BODY(T, BCUR, BNXT) {                                              \
    const int P = (T) & 1;                                                      \
    const u16* Ac = As[P];                                                      \
    const int kA = ((T) + 1) * 64, kB = ((T) + 2) * 64;                         \
    const bool m1 = (T) + 1 < NT, m2 = (T) + 2 < NT;                            \
    /* ph0: q0 MFMA; read A q1; stage A(T+1) */                                 \
    RD_AQ(aY, Ac, 1);                                                           \
    if (m1) STG_A_ALL(P ^ 1, kA);                                               \
    __builtin_amdgcn_s_barrier();                                               \
    asm volatile("s_waitcnt lgkmcnt(4)" ::: "memory");                          \
    __builtin_amdgcn_sched_barrier(0);                                          \
    MFMA_Q(0, aX, BCUR);                                                        \
    __builtin_amdgcn_s_barrier();                                               \
    /* ph1: q1 MFMA; read A q2; stage B(T+2) h0 */                              \
    RD_AQ(aX, Ac, 2);                                                           \
    if (m2) STG_B_H(0, P, kB);                                                  \
    __builtin_amdgcn_s_barrier();                                               \
    asm volatile("s_waitcnt lgkmcnt(4)" ::: "memory");                          \
    __builtin_amdgcn_sched_barrier(0);                                          \
    MFMA_Q(1, aY, BCUR);                                                        \
    __builtin_amdgcn_s_barrier();                                               \
    /* ph2: q2 MFMA; read A q3; stage B(T+2) h1; counted vmcnt */               \
    RD_AQ(aY, Ac, 3);                                                           \
    if (m2) STG_B_H(1, P, kB);                                                  \
    __builtin_amdgcn_s_barrier();                                               \
    asm volatile("s_waitcnt lgkmcnt(4)" ::: "memory");                          \
    __builtin_amdgcn_sched_barrier(0);                                          \
    MFMA_Q(2, aX, BCUR);                                                        \
    if (m2) { asm volatile("s_waitcnt vmcnt(4)" ::: "memory"); }                \
    else    { asm volatile("s_waitcnt vmcnt(0)" ::: "memory"); }                \
    __builtin_amdgcn_s_barrier();                                               \
    /* ph3: q3 MFMA; read B(T+1) frags + A(T+1) q0  [12-read phase] */          \
    if (m1) { RD_B(BNXT, Bs[P ^ 1]); RD_AQ(aX, As[P ^ 1], 0); }                 \
    __builtin_amdgcn_s_barrier();                                               \
    if (m1) { asm volatile("s_waitcnt lgkmcnt(12)" ::: "memory"); }             \
    else    { asm volatile("s_waitcnt lgkmcnt(0)"  ::: "memory"); }             \
    __builtin_amdgcn_sched_barrier(0);                                          \
    MFMA_Q(3, aY, BCUR);                                                        \
    __builtin_amdgcn_s_barrier(); }

#pragma unroll
    for (int i = 0; i < 8; ++i)
#pragma unroll
        for (int j = 0; j < 4; ++j) acc[i][j] = floatx4{0.f, 0.f, 0.f, 0.f};

    short8 Bu[4][2], Bv[4][2];
    short8 aX[2][2], aY[2][2];

    // Prologue: stage tile0 (B x4, A x4) + B(1) x4; wait tile0, read its
    // B frags + A q0. Issue order matters for the vmcnt ledger.
    STG_B_H(0, 0, 0); STG_B_H(1, 0, 0);
    STG_A_ALL(0, 0);
    STG_B_H(0, 1, 64); STG_B_H(1, 1, 64);
    asm volatile("s_waitcnt vmcnt(4)" ::: "memory");
    __builtin_amdgcn_s_barrier();
    RD_B(Bu, Bs[0]);
    RD_AQ(aX, As[0], 0);

    for (int t2 = 0; t2 < NT; t2 += 2) {
        TILE_BODY(t2,     Bu, Bv);
        TILE_BODY(t2 + 1, Bv, Bu);
    }
#undef STG_A_ALL
#undef STG_B_H
#undef RD_AQ
#undef RD_B
#undef MFMA_Q
#undef TILE_BODY
}

// ---------------------------------------------------------------------------
// Fused QKV GEMM: [Q|K|V](4096x6144) = X @ Wall^T + ball. Q,K row-major;
// V written transposed. 256x256 tiles -> grid (24,16).
// ---------------------------------------------------------------------------
__launch_bounds__(512, 2)
__global__ void gemm_qkv(const u16* __restrict__ A, const u16* __restrict__ W,
                         const u16* __restrict__ bias,
                         u16* __restrict__ Qb, u16* __restrict__ Kb,
                         u16* __restrict__ VtG) {
    const int m0 = blockIdx.y * 256;
    const int n0 = blockIdx.x * 256;
    floatx4 acc[8][4];
    gemm256_core(A, W, m0, n0, acc);

    const int tid  = threadIdx.x;
    const int lane = tid & 63;
    const int w    = tid >> 6;
    const int qm   = lane & 15;
    const int quad = lane >> 4;
    const int wm   = (w >> 2) * 128;
    const int wn   = (w & 3) * 64;

    const int buf = n0 >> 11;  // 0=Q, 1=K, 2=V (block-uniform: 2048%256==0)
    if (buf < 2) {
        u16* Y = (buf == 0) ? Qb : Kb;
#pragma unroll
        for (int nt = 0; nt < 4; ++nt) {
            const int gcol = n0 + wn + nt * 16 + qm;
            const int col  = gcol & 2047;
            const float bv = b2f(bias[gcol]);
#pragma unroll
            for (int mt = 0; mt < 8; ++mt) {
                const int rbase = m0 + wm + mt * 16 + quad * 4;
#pragma unroll
                for (int r = 0; r < 4; ++r)
                    Y[(size_t)(rbase + r) * DM + col] = f2b(acc[mt][nt][r] + bv);
            }
        }
    } else {
#pragma unroll
        for (int nt = 0; nt < 4; ++nt) {
            const int gcol = n0 + wn + nt * 16 + qm;
            const int col  = gcol & 2047;            // d-index
            const float bv = b2f(bias[gcol]);
#pragma unroll
            for (int mt = 0; mt < 8; ++mt) {
                const int rbase = m0 + wm + mt * 16 + quad * 4;
                u16 tmp[4];
#pragma unroll
                for (int r = 0; r < 4; ++r)
                    tmp[r] = f2b(acc[mt][nt][r] + bv);
                *(short4v*)&VtG[(size_t)col * SEQ + rbase] = *(const short4v*)tmp;
            }
        }
    }
}

// ---------------------------------------------------------------------------
// Output GEMM: d_out = Ab @ Wo^T + bo, written in the harness's dtype.
// 256x256 tiles -> grid (8,16).
// ---------------------------------------------------------------------------
__launch_bounds__(512, 2)
__global__ void gemm_out(const u16* __restrict__ A, const u16* __restrict__ W,
                         const u16* __restrict__ bias, void* __restrict__ out,
                         const int* __restrict__ flag) {
    const int m0 = blockIdx.y * 256;
    const int n0 = blockIdx.x * 256;
    floatx4 acc[8][4];
    gemm256_core(A, W, m0, n0, acc);

    const int tid  = threadIdx.x;
    const int lane = tid & 63;
    const int w    = tid >> 6;
    const int qm   = lane & 15;
    const int quad = lane >> 4;
    const int wm   = (w >> 2) * 128;
    const int wn   = (w & 3) * 64;
    const int N    = DM;

    const int f = *flag;
#pragma unroll
    for (int nt = 0; nt < 4; ++nt) {
        const int col = n0 + wn + nt * 16 + qm;
        const float bv = b2f(bias[col]);
#pragma unroll
        for (int mt = 0; mt < 8; ++mt) {
            const int rbase = m0 + wm + mt * 16 + quad * 4;
#pragma unroll
            for (int r = 0; r < 4; ++r) {
                const float v = acc[mt][nt][r] + bv;
                if (f) ((u16*)out)[(size_t)(rbase + r) * N + col] = f2b(v);
                else   ((float*)out)[(size_t)(rbase + r) * N + col] = v;
            }
        }
    }
}

// ---------------------------------------------------------------------------
// Flash attention: unchanged this round (512 thr, 8 waves x 16 q-rows,
// causal balance flip, BK=64, fixed-shift softmax, register-prefetch dbuf).
// ---------------------------------------------------------------------------
__launch_bounds__(512)
__global__ void attn_kernel(const u16* __restrict__ Q, const u16* __restrict__ K,
                            const u16* __restrict__ Vt, u16* __restrict__ O,
                            const int* __restrict__ is_causal_p) {
    __shared__ __align__(16) u16 Ks[64][136];
    __shared__ __align__(16) u16 Vts[128][72];
    __shared__ __align__(16) u16 Pb[8][16][72];

    const int tid  = threadIdx.x;
    const int lane = tid & 63;
    const int w    = tid >> 6;                 // 0..7
    const int qm   = lane & 15;
    const int quad = lane >> 4;
    const int xt   = ((blockIdx.y >> 3) & 1) ? (gridDim.x - 1 - blockIdx.x)
                                             : blockIdx.x;
    const int q0   = xt * 128;
    const int h    = blockIdx.y;
    const int causal = *is_causal_p;
    const float scale = 0.08838834764831845f;  // 1/sqrt(128)
    const float SHIFT = 16.0f;                 // exact (softmax shift-invariant)

    short8 qf[4];
    {
        const u16* qptr = Q + (size_t)(q0 + w * 16 + qm) * DM + h * HD;
#pragma unroll
        for (int kc = 0; kc < 4; kc++)
            qf[kc] = *(const short8*)&qptr[kc * 32 + quad * 8];
    }

    floatx4 o[8];
#pragma unroll
    for (int dt = 0; dt < 8; dt++) o[dt] = floatx4{0.f, 0.f, 0.f, 0.f};
    float l_part[4] = {0.f, 0.f, 0.f, 0.f};

    const int jend = causal ? (q0 + 128) : SEQ;

    // staging map (512 thr): chunk c = tid + p*512
    const int kr0 = tid >> 4;            // K row (p adds 32)
    const int kc8 = (tid & 15) * 8;
    const int vd0 = tid >> 3;            // V d   (p adds 64)
    const int vc8 = (tid & 7) * 8;

    short8 kreg[2], vreg[2];
#pragma unroll
    for (int p = 0; p < 2; p++) {
        kreg[p] = *(const short8*)&K[(size_t)(kr0 + p * 32) * DM + h * HD + kc8];
        vreg[p] = *(const short8*)&Vt[(size_t)(h * HD + vd0 + p * 64) * SEQ + vc8];
    }

    for (int j0 = 0; j0 < jend; j0 += 64) {
        // commit prefetched tile to LDS
#pragma unroll
        for (int p = 0; p < 2; p++) {
            *(short8*)&Ks[kr0 + p * 32][kc8] = kreg[p];
            *(short8*)&Vts[vd0 + p * 64][vc8] = vreg[p];
        }
        __syncthreads();

        // prefetch next tile into regs (latency hidden behind compute)
        const int jn = (j0 + 64 < jend) ? j0 + 64 : 0;
#pragma unroll
        for (int p = 0; p < 2; p++) {
            kreg[p] = *(const short8*)&K[(size_t)(jn + kr0 + p * 32) * DM + h * HD + kc8];
            vreg[p] = *(const short8*)&Vt[(size_t)(h * HD + vd0 + p * 64) * SEQ + jn + vc8];
        }

        // S = Q @ K^T
        floatx4 s[4];
#pragma unroll
        for (int nt = 0; nt < 4; nt++) s[nt] = floatx4{0.f, 0.f, 0.f, 0.f};
#pragma unroll
        for (int kc = 0; kc < 4; kc++)
#pragma unroll
            for (int nt = 0; nt < 4; nt++) {
                short8 b = *(const short8*)&Ks[nt * 16 + qm][kc * 32 + quad * 8];
                s[nt] = __builtin_amdgcn_mfma_f32_16x16x32_bf16(qf[kc], b, s[nt], 0, 0, 0);
            }

        // P = exp(S*scale - SHIFT), masked; per-lane partial row sums
        const bool mask = causal && (j0 + 64 > q0 + w * 16);
#pragma unroll
        for (int r = 0; r < 4; r++) {
            const int qg = q0 + w * 16 + quad * 4 + r;
#pragma unroll
            for (int nt = 0; nt < 4; nt++) {
                float v = fmaf(s[nt][r], scale, -SHIFT);
                if (mask && (j0 + nt * 16 + qm > qg)) v = -1e30f;
                const float p = __expf(v);
                l_part[r] += p;
                Pb[w][quad * 4 + r][nt * 16 + qm] = f2b(p);
            }
        }
        asm volatile("s_waitcnt lgkmcnt(0)" ::: "memory");  // Pb is wave-local

        // O += P @ V
#pragma unroll
        for (int kc = 0; kc < 2; kc++) {
            short8 pf = *(const short8*)&Pb[w][qm][kc * 32 + quad * 8];
#pragma unroll
            for (int dt = 0; dt < 8; dt++) {
                short8 b = *(const short8*)&Vts[dt * 16 + qm][kc * 32 + quad * 8];
                o[dt] = __builtin_amdgcn_mfma_f32_16x16x32_bf16(pf, b, o[dt], 0, 0, 0);
            }
        }
        __syncthreads();   // all waves done reading Ks/Vts before next commit
    }

    // Epilogue: quad-local l reduction, normalize, store
#pragma unroll
    for (int r = 0; r < 4; r++) {
        float l = l_part[r];
#pragma unroll
        for (int off = 8; off >= 1; off >>= 1)
            l += __shfl_xor(l, off, 64);
        const float inv = 1.0f / l;
        const int qg = q0 + w * 16 + quad * 4 + r;
#pragma unroll
        for (int dt = 0; dt < 8; dt++) {
            const int d = h * HD + dt * 16 + qm;
            O[(size_t)qg * DM + d] = f2b(o[dt][r] * inv);
        }
    }
}

// ---------------------------------------------------------------------------
extern "C" void kernel_launch(void* const* d_in, const int* in_sizes, int n_in,
                              void* d_out, int out_size, void* d_ws, size_t ws_size,
                              hipStream_t stream) {
    const int* isc = (const int*)d_in[9];

    int* flag = (int*)d_ws;
    u16* base = (u16*)((char*)d_ws + 256);

    const int NX = SEQ * DM;       // 8388608
    const int NW = DM * DM;        // 4194304
    const int NB = DM;

    // ws layout (u16 elems from base):
    unsigned long long off = 0;
    const unsigned long long oXc   = off; off += NX;
    const unsigned long long oWall = off; off += 3ull * NW;  // Wq,Wk,Wv
    const unsigned long long oWo   = off; off += NW;
    const unsigned long long oBall = off; off += 3ull * NB;  // bq,bk,bv
    const unsigned long long oBo   = off; off += NB;
    const unsigned long long oQ    = off; off += NX;
    const unsigned long long oK    = off; off += NX;
    const unsigned long long oVt   = off; off += NX;
    const unsigned long long oA    = off; off += NX;

    detect_dtype<<<1, 256, 0, stream>>>((const u16*)d_in[0], flag);

    ConvArgs ca;
    const unsigned long long dsts[9] = {oXc, oWall, oBall, oWall + NW, oBall + NB,
                                        oWall + 2ull * NW, oBall + 2ull * NB, oWo, oBo};
    for (int i = 0; i < 9; i++) {
        ca.src[i] = d_in[i];
        ca.dstoff[i] = dsts[i];
        ca.n[i] = in_sizes[i];
    }
    convert_all<<<dim3(NX / 8 / 256, 9), 256, 0, stream>>>(ca, base, flag);

    gemm_qkv<<<dim3(3 * DM / 256, SEQ / 256), 512, 0, stream>>>(
        base + oXc, base + oWall, base + oBall,
        base + oQ, base + oK, base + oVt);

    attn_kernel<<<dim3(SEQ / 128, NH), 512, 0, stream>>>(
        base + oQ, base + oK, base + oVt, base + oA, isc);

    gemm_out<<<dim3(DM / 256, SEQ / 256), 512, 0, stream>>>(
        base + oA, base + oWo, base + oBo, d_out, flag);
}

// Round 5
// 441.032 us; speedup vs baseline: 1.1104x; 1.1104x over previous
//
#include <hip/hip_runtime.h>
#include <hip/hip_bf16.h>

typedef unsigned short u16;
typedef __attribute__((ext_vector_type(8))) short short8;
typedef __attribute__((ext_vector_type(4))) short short4v;
typedef __attribute__((ext_vector_type(4))) float floatx4;

constexpr int SEQ = 4096;
constexpr int DM  = 2048;
constexpr int NH  = 16;
constexpr int HD  = 128;

__device__ inline u16 f2b(float f) {
    __hip_bfloat16 h = __float2bfloat16(f);
    return *reinterpret_cast<u16*>(&h);
}
__device__ inline float b2f(u16 u) {
    __hip_bfloat16 h = *reinterpret_cast<__hip_bfloat16*>(&u);
    return __bfloat162float(h);
}

__device__ __forceinline__ void async_copy16(const u16* g, u16* lds_base) {
    __builtin_amdgcn_global_load_lds(
        (const __attribute__((address_space(1))) unsigned int*)g,
        (__attribute__((address_space(3))) unsigned int*)lds_base,
        16, 0, 0);
}

template<int N> __device__ __forceinline__ void wait_vm() {
    if constexpr (N == 0) asm volatile("s_waitcnt vmcnt(0)" ::: "memory");
    else if constexpr (N == 2) asm volatile("s_waitcnt vmcnt(2)" ::: "memory");
    else if constexpr (N == 3) asm volatile("s_waitcnt vmcnt(3)" ::: "memory");
    else if constexpr (N == 4) asm volatile("s_waitcnt vmcnt(4)" ::: "memory");
}
template<int N> __device__ __forceinline__ void wait_lgkm() {
    if constexpr (N == 0) asm volatile("s_waitcnt lgkmcnt(0)" ::: "memory");
    else if constexpr (N == 4) asm volatile("s_waitcnt lgkmcnt(4)" ::: "memory");
    else if constexpr (N == 8) asm volatile("s_waitcnt lgkmcnt(8)" ::: "memory");
    else if constexpr (N == 10) asm volatile("s_waitcnt lgkmcnt(10)" ::: "memory");
    else if constexpr (N == 12) asm volatile("s_waitcnt lgkmcnt(12)" ::: "memory");
}

// ---------------------------------------------------------------------------
__global__ void detect_dtype(const u16* __restrict__ X, int* __restrict__ flag) {
    __shared__ int cnt;
    if (threadIdx.x == 0) cnt = 0;
    __syncthreads();
    int local = 0;
    for (int i = threadIdx.x; i < 4096; i += 256) {
        int e = (X[i] >> 7) & 0xFF;
        if (e >= 0x3C && e <= 0x8D) local++;
    }
    atomicAdd(&cnt, local);
    __syncthreads();
    if (threadIdx.x == 0) *flag = (cnt >= 3890) ? 1 : 0;
}

// One launch converts all 9 float tensors (bf16 passthrough or fp32 round).
struct ConvArgs {
    const void* src[9];
    unsigned long long dstoff[9];  // u16-element offset from base
    int n[9];
};
__global__ void convert_all(ConvArgs a, u16* __restrict__ base,
                            const int* __restrict__ flag) {
    const int t = blockIdx.y;
    const int n = a.n[t];
    const int i = (blockIdx.x * blockDim.x + threadIdx.x) * 8;
    if (i >= n) return;
    u16* out = base + a.dstoff[t];
    if (*flag) {
        *(short8*)&out[i] = *(const short8*)&((const u16*)a.src[t])[i];
    } else {
        const float* p = (const float*)a.src[t];
        u16 tmp[8];
#pragma unroll
        for (int j = 0; j < 8; j++) tmp[j] = f2b(p[i + j]);
        *(short8*)&out[i] = *(const short8*)tmp;
    }
}

// ---------------------------------------------------------------------------
// 256 x (NF*64/... = NF*16*4) 8-phase GEMM core (R4-verified schedule,
// templated on NF = number of 16-col fragments per wave).
//   BM=256, BN=NF*64, BK=64, 512 thr = 8 waves (2M x 4N), wave out 128x(NF*16).
//   NF=4 -> BN=256 (R4-verified), NF=3 -> BN=192, NF=2 -> BN=128.
//   Grid geometry motive: qkv NF=3 -> 32x16=512 blocks = 2 EXACT rounds;
//   out NF=2 -> 16x16=256 = 1 EXACT round (tail-round waste eliminated).
//   LDS: 2 parity bufs x (A 32KB + B NF*8KB).
//   Phase = {4 (or 2NF+4) ds_read || stage -> barrier -> counted lgkm ->
//            sched_barrier(0) -> setprio(1) 4*NF MFMA setprio(0) -> barrier}.
//   Stage map: t.ph0: A(t+1) x4; t.ph1: B(t+2) slots [0,ceil(NF/2));
//              t.ph2: B(t+2) remaining slots.
//   vmcnt ledger (per-wave FIFO) at end t.ph2: {B(t+1)xNF, A(t+1)x4,
//     B(t+2)xNF} -> vmcnt(NF) forces tile t+1 landed, B(t+2) stays in flight.
//   lgkm ledger: ph3 issues 2NF+4 reads -> wait lgkmcnt(2NF+4) drains the
//     prior phase's 4; ph0/1/2 wait lgkmcnt(4).
// ---------------------------------------------------------------------------
template<int NF>
__device__ __forceinline__ void gemm_core(
    const u16* __restrict__ A, const u16* __restrict__ W,
    int m0, int n0, floatx4 (&acc)[8][NF])
{
    __shared__ __align__(16) u16 As[2][16384];       // 256 x 64 per parity
    __shared__ __align__(16) u16 Bs[2][NF * 4096];   // NF*64 x 64 per parity
    constexpr int K  = DM;
    constexpr int NT = K / 64;   // 32 (even)
    constexpr int B1N = (NF + 1) / 2;   // B slots staged at ph1

    const int tid  = threadIdx.x;
    const int lane = tid & 63;
    const int w    = tid >> 6;            // 0..7
    const int qm   = lane & 15;
    const int quad = lane >> 4;
    const int wm   = (w >> 2) * 128;      // wave rows: 0 / 128
    const int wn   = (w & 3) * (NF * 16); // wave cols

    // staging: thread t covers LDS linear [slot*8192B + tid*16B, +16B)
    // source pre-swizzle: global granule = (t&7) ^ (row&7)
    const int srow = tid >> 3;                       // 0..63
    const int scol = ((tid & 7) ^ (srow & 7)) * 8;   // elems

    // frag-read swizzle: physical granule = (kh*4+quad) ^ (row&7); row&7==qm&7
    const int fo0 = (quad ^ (qm & 7)) * 8;
    const int fo1 = fo0 ^ 32;

    const u16* Ag = A + (size_t)(m0 + srow) * K + scol;
    const u16* Wg = W + (size_t)(n0 + srow) * K + scol;

#define STG_A_ALL(par, k0) {                                                    \
    async_copy16(Ag + (size_t)0 * 64 * K + (k0), &As[par][0 * 4096 + w * 512]); \
    async_copy16(Ag + (size_t)1 * 64 * K + (k0), &As[par][1 * 4096 + w * 512]); \
    async_copy16(Ag + (size_t)2 * 64 * K + (k0), &As[par][2 * 4096 + w * 512]); \
    async_copy16(Ag + (size_t)3 * 64 * K + (k0), &As[par][3 * 4096 + w * 512]); }
#define STG_B_SLOT(s, par, k0)                                                  \
    async_copy16(Wg + (size_t)(s) * 64 * K + (k0), &Bs[par][(s) * 4096 + w * 512]);

#define RD_AQ(dst, Abase, q) {                                                  \
    dst[0][0] = *(const short8*)&Abase[(wm + (2*(q)) * 16 + qm) * 64 + fo0];    \
    dst[0][1] = *(const short8*)&Abase[(wm + (2*(q)) * 16 + qm) * 64 + fo1];    \
    dst[1][0] = *(const short8*)&Abase[(wm + (2*(q)+1) * 16 + qm) * 64 + fo0];  \
    dst[1][1] = *(const short8*)&Abase[(wm + (2*(q)+1) * 16 + qm) * 64 + fo1]; }

#define RD_B(dst, Bbase) {                                                      \
    _Pragma("unroll")                                                           \
    for (int nt = 0; nt < NF; ++nt) {                                           \
        dst[nt][0] = *(const short8*)&Bbase[(wn + nt * 16 + qm) * 64 + fo0];    \
        dst[nt][1] = *(const short8*)&Bbase[(wn + nt * 16 + qm) * 64 + fo1];    \
    } }

#define MFMA_Q(q, aR, bR) {                                                     \
    __builtin_amdgcn_s_setprio(1);                                              \
    _Pragma("unroll")                                                           \
    for (int nt = 0; nt < NF; ++nt) {                                           \
        acc[2*(q)][nt]   = __builtin_amdgcn_mfma_f32_16x16x32_bf16(aR[0][0], bR[nt][0], acc[2*(q)][nt],   0, 0, 0); \
        acc[2*(q)][nt]   = __builtin_amdgcn_mfma_f32_16x16x32_bf16(aR[0][1], bR[nt][1], acc[2*(q)][nt],   0, 0, 0); \
        acc[2*(q)+1][nt] = __builtin_amdgcn_mfma_f32_16x16x32_bf16(aR[1][0], bR[nt][0], acc[2*(q)+1][nt], 0, 0, 0); \
        acc[2*(q)+1][nt] = __builtin_amdgcn_mfma_f32_16x16x32_bf16(aR[1][1], bR[nt][1], acc[2*(q)+1][nt], 0, 0, 0); \
    }                                                                           \
    __builtin_amdgcn_s_setprio(0); }

// One K-tile = 4 phases. BCUR = B frags of tile T; BNXT filled at ph3.
#define TILE_BODY(T, BCUR, BNXT) {                                              \
    const int P = (T) & 1;                                                      \
    const u16* Ac = As[P];                                                      \
    const int kA = ((T) + 1) * 64, kB = ((T) + 2) * 64;                         \
    const bool m1 = (T) + 1 < NT, m2 = (T) + 2 < NT;                            \
    /* ph0: q0 MFMA; read A q1; stage A(T+1) */                                 \
    RD_AQ(aY, Ac, 1);                                                           \
    if (m1) STG_A_ALL(P ^ 1, kA);                                               \
    __builtin_amdgcn_s_barrier();                                               \
    wait_lgkm<4>();                                                             \
    __builtin_amdgcn_sched_barrier(0);                                          \
    MFMA_Q(0, aX, BCUR);                                                        \
    __builtin_amdgcn_s_barrier();                                               \
    /* ph1: q1 MFMA; read A q2; stage B(T+2) first slots */                     \
    RD_AQ(aX, Ac, 2);                                                           \
    if (m2) { _Pragma("unroll")                                                 \
              for (int s = 0; s < B1N; ++s) STG_B_SLOT(s, P, kB); }             \
    __builtin_amdgcn_s_barrier();                                               \
    wait_lgkm<4>();                                                             \
    __builtin_amdgcn_sched_barrier(0);                                          \
    MFMA_Q(1, aY, BCUR);                                                        \
    __builtin_amdgcn_s_barrier();                                               \
    /* ph2: q2 MFMA; read A q3; stage B(T+2) rest; counted vmcnt */             \
    RD_AQ(aY, Ac, 3);                                                           \
    if (m2) { _Pragma("unroll")                                                 \
              for (int s = B1N; s < NF; ++s) STG_B_SLOT(s, P, kB); }            \
    __builtin_amdgcn_s_barrier();                                               \
    wait_lgkm<4>();                                                             \
    __builtin_amdgcn_sched_barrier(0);                                          \
    MFMA_Q(2, aX, BCUR);                                                        \
    if (m2) wait_vm<NF>(); else wait_vm<0>();                                   \
    __builtin_amdgcn_s_barrier();                                               \
    /* ph3: q3 MFMA; read B(T+1) frags + A(T+1) q0  [2NF+4-read phase] */       \
    if (m1) { RD_B(BNXT, Bs[P ^ 1]); RD_AQ(aX, As[P ^ 1], 0); }                 \
    __builtin_amdgcn_s_barrier();                                               \
    if (m1) wait_lgkm<2 * NF + 4>(); else wait_lgkm<0>();                       \
    __builtin_amdgcn_sched_barrier(0);                                          \
    MFMA_Q(3, aY, BCUR);                                                        \
    __builtin_amdgcn_s_barrier(); }

#pragma unroll
    for (int i = 0; i < 8; ++i)
#pragma unroll
        for (int j = 0; j < NF; ++j) acc[i][j] = floatx4{0.f, 0.f, 0.f, 0.f};

    short8 Bu[NF][2], Bv[NF][2];
    short8 aX[2][2], aY[2][2];

    // Prologue (FIFO order matters for the vmcnt ledger):
    //   B(0) xNF, A(0) x4, B(1) xNF -> vmcnt(NF) = tile0 landed, B(1) flying.
#pragma unroll
    for (int s = 0; s < NF; ++s) STG_B_SLOT(s, 0, 0);
    STG_A_ALL(0, 0);
#pragma unroll
    for (int s = 0; s < NF; ++s) STG_B_SLOT(s, 1, 64);
    wait_vm<NF>();
    __builtin_amdgcn_s_barrier();
    RD_B(Bu, Bs[0]);
    RD_AQ(aX, As[0], 0);

    for (int t2 = 0; t2 < NT; t2 += 2) {
        TILE_BODY(t2,     Bu, Bv);
        TILE_BODY(t2 + 1, Bv, Bu);
    }
#undef STG_A_ALL
#undef STG_B_SLOT
#undef RD_AQ
#undef RD_B
#undef MFMA_Q
#undef TILE_BODY
}

// ---------------------------------------------------------------------------
// Fused QKV GEMM: [Q|K|V](4096x6144) = X @ Wall^T + ball. Q,K row-major;
// V written transposed. NF=3 -> 256x192 tiles, grid (32,16) = 512 blocks
// = EXACTLY 2 full rounds at 1 block/CU. A 192-wide tile can straddle the
// Q/K/V 2048-col boundaries, so buf is resolved per 16-col fragment
// (boundary is a multiple of 16 -> each fragment is in exactly one buffer).
// ---------------------------------------------------------------------------
__launch_bounds__(512, 2)
__global__ void gemm_qkv(const u16* __restrict__ A, const u16* __restrict__ W,
                         const u16* __restrict__ bias,
                         u16* __restrict__ Qb, u16* __restrict__ Kb,
                         u16* __restrict__ VtG) {
    const int m0 = blockIdx.y * 256;
    const int n0 = blockIdx.x * 192;
    floatx4 acc[8][3];
    gemm_core<3>(A, W, m0, n0, acc);

    const int tid  = threadIdx.x;
    const int lane = tid & 63;
    const int w    = tid >> 6;
    const int qm   = lane & 15;
    const int quad = lane >> 4;
    const int wm   = (w >> 2) * 128;
    const int wn   = (w & 3) * 48;

#pragma unroll
    for (int nt = 0; nt < 3; ++nt) {
        const int gc0  = n0 + wn + nt * 16;      // wave-uniform fragment base
        const int buf  = gc0 >> 11;              // 0=Q, 1=K, 2=V
        const int gcol = gc0 + qm;
        const int col  = gcol & 2047;
        const float bv = b2f(bias[gcol]);
        if (buf < 2) {
            u16* Y = (buf == 0) ? Qb : Kb;
#pragma unroll
            for (int mt = 0; mt < 8; ++mt) {
                const int rbase = m0 + wm + mt * 16 + quad * 4;
#pragma unroll
                for (int r = 0; r < 4; ++r)
                    Y[(size_t)(rbase + r) * DM + col] = f2b(acc[mt][nt][r] + bv);
            }
        } else {
#pragma unroll
            for (int mt = 0; mt < 8; ++mt) {
                const int rbase = m0 + wm + mt * 16 + quad * 4;
                u16 tmp[4];
#pragma unroll
                for (int r = 0; r < 4; ++r)
                    tmp[r] = f2b(acc[mt][nt][r] + bv);
                *(short4v*)&VtG[(size_t)col * SEQ + rbase] = *(const short4v*)tmp;
            }
        }
    }
}

// ---------------------------------------------------------------------------
// Output GEMM: d_out = Ab @ Wo^T + bo, written in the harness's dtype.
// NF=2 -> 256x128 tiles, grid (16,16) = 256 blocks = EXACTLY 1 full round
// (was 8x16=128 blocks = half the machine idle).
// ---------------------------------------------------------------------------
__launch_bounds__(512, 2)
__global__ void gemm_out(const u16* __restrict__ A, const u16* __restrict__ W,
                         const u16* __restrict__ bias, void* __restrict__ out,
                         const int* __restrict__ flag) {
    const int m0 = blockIdx.y * 256;
    const int n0 = blockIdx.x * 128;
    floatx4 acc[8][2];
    gemm_core<2>(A, W, m0, n0, acc);

    const int tid  = threadIdx.x;
    const int lane = tid & 63;
    const int w    = tid >> 6;
    const int qm   = lane & 15;
    const int quad = lane >> 4;
    const int wm   = (w >> 2) * 128;
    const int wn   = (w & 3) * 32;
    const int N    = DM;

    const int f = *flag;
#pragma unroll
    for (int nt = 0; nt < 2; ++nt) {
        const int col = n0 + wn + nt * 16 + qm;
        const float bv = b2f(bias[col]);
#pragma unroll
        for (int mt = 0; mt < 8; ++mt) {
            const int rbase = m0 + wm + mt * 16 + quad * 4;
#pragma unroll
            for (int r = 0; r < 4; ++r) {
                const float v = acc[mt][nt][r] + bv;
                if (f) ((u16*)out)[(size_t)(rbase + r) * N + col] = f2b(v);
                else   ((float*)out)[(size_t)(rbase + r) * N + col] = v;
            }
        }
    }
}

// ---------------------------------------------------------------------------
// Flash attention (512 thr, 8 waves x 16 q-rows, causal balance flip, BK=64,
// fixed-shift softmax, register-prefetch dbuf) + T5 setprio around MFMA
// clusters (m191: +4-7% on attn; blocks are independent -> wave role split).
// ---------------------------------------------------------------------------
__launch_bounds__(512)
__global__ void attn_kernel(const u16* __restrict__ Q, const u16* __restrict__ K,
                            const u16* __restrict__ Vt, u16* __restrict__ O,
                            const int* __restrict__ is_causal_p) {
    __shared__ __align__(16) u16 Ks[64][136];
    __shared__ __align__(16) u16 Vts[128][72];
    __shared__ __align__(16) u16 Pb[8][16][72];

    const int tid  = threadIdx.x;
    const int lane = tid & 63;
    const int w    = tid >> 6;                 // 0..7
    const int qm   = lane & 15;
    const int quad = lane >> 4;
    const int xt   = ((blockIdx.y >> 3) & 1) ? (gridDim.x - 1 - blockIdx.x)
                                             : blockIdx.x;
    const int q0   = xt * 128;
    const int h    = blockIdx.y;
    const int causal = *is_causal_p;
    const float scale = 0.08838834764831845f;  // 1/sqrt(128)
    const float SHIFT = 16.0f;                 // exact (softmax shift-invariant)

    short8 qf[4];
    {
        const u16* qptr = Q + (size_t)(q0 + w * 16 + qm) * DM + h * HD;
#pragma unroll
        for (int kc = 0; kc < 4; kc++)
            qf[kc] = *(const short8*)&qptr[kc * 32 + quad * 8];
    }

    floatx4 o[8];
#pragma unroll
    for (int dt = 0; dt < 8; dt++) o[dt] = floatx4{0.f, 0.f, 0.f, 0.f};
    float l_part[4] = {0.f, 0.f, 0.f, 0.f};

    const int jend = causal ? (q0 + 128) : SEQ;

    // staging map (512 thr): chunk c = tid + p*512
    const int kr0 = tid >> 4;            // K row (p adds 32)
    const int kc8 = (tid & 15) * 8;
    const int vd0 = tid >> 3;            // V d   (p adds 64)
    const int vc8 = (tid & 7) * 8;

    short8 kreg[2], vreg[2];
#pragma unroll
    for (int p = 0; p < 2; p++) {
        kreg[p] = *(const short8*)&K[(size_t)(kr0 + p * 32) * DM + h * HD + kc8];
        vreg[p] = *(const short8*)&Vt[(size_t)(h * HD + vd0 + p * 64) * SEQ + vc8];
    }

    for (int j0 = 0; j0 < jend; j0 += 64) {
        // commit prefetched tile to LDS
#pragma unroll
        for (int p = 0; p < 2; p++) {
            *(short8*)&Ks[kr0 + p * 32][kc8] = kreg[p];
            *(short8*)&Vts[vd0 + p * 64][vc8] = vreg[p];
        }
        __syncthreads();

        // prefetch next tile into regs (latency hidden behind compute)
        const int jn = (j0 + 64 < jend) ? j0 + 64 : 0;
#pragma unroll
        for (int p = 0; p < 2; p++) {
            kreg[p] = *(const short8*)&K[(size_t)(jn + kr0 + p * 32) * DM + h * HD + kc8];
            vreg[p] = *(const short8*)&Vt[(size_t)(h * HD + vd0 + p * 64) * SEQ + jn + vc8];
        }

        // S = Q @ K^T
        floatx4 s[4];
#pragma unroll
        for (int nt = 0; nt < 4; nt++) s[nt] = floatx4{0.f, 0.f, 0.f, 0.f};
        __builtin_amdgcn_s_setprio(1);
#pragma unroll
        for (int kc = 0; kc < 4; kc++)
#pragma unroll
            for (int nt = 0; nt < 4; nt++) {
                short8 b = *(const short8*)&Ks[nt * 16 + qm][kc * 32 + quad * 8];
                s[nt] = __builtin_amdgcn_mfma_f32_16x16x32_bf16(qf[kc], b, s[nt], 0, 0, 0);
            }
        __builtin_amdgcn_s_setprio(0);

        // P = exp(S*scale - SHIFT), masked; per-lane partial row sums
        const bool mask = causal && (j0 + 64 > q0 + w * 16);
#pragma unroll
        for (int r = 0; r < 4; r++) {
            const int qg = q0 + w * 16 + quad * 4 + r;
#pragma unroll
            for (int nt = 0; nt < 4; nt++) {
                float v = fmaf(s[nt][r], scale, -SHIFT);
                if (mask && (j0 + nt * 16 + qm > qg)) v = -1e30f;
                const float p = __expf(v);
                l_part[r] += p;
                Pb[w][quad * 4 + r][nt * 16 + qm] = f2b(p);
            }
        }
        asm volatile("s_waitcnt lgkmcnt(0)" ::: "memory");  // Pb is wave-local

        // O += P @ V
        __builtin_amdgcn_s_setprio(1);
#pragma unroll
        for (int kc = 0; kc < 2; kc++) {
            short8 pf = *(const short8*)&Pb[w][qm][kc * 32 + quad * 8];
#pragma unroll
            for (int dt = 0; dt < 8; dt++) {
                short8 b = *(const short8*)&Vts[dt * 16 + qm][kc * 32 + quad * 8];
                o[dt] = __builtin_amdgcn_mfma_f32_16x16x32_bf16(pf, b, o[dt], 0, 0, 0);
            }
        }
        __builtin_amdgcn_s_setprio(0);
        __syncthreads();   // all waves done reading Ks/Vts before next commit
    }

    // Epilogue: quad-local l reduction, normalize, store
#pragma unroll
    for (int r = 0; r < 4; r++) {
        float l = l_part[r];
#pragma unroll
        for (int off = 8; off >= 1; off >>= 1)
            l += __shfl_xor(l, off, 64);
        const float inv = 1.0f / l;
        const int qg = q0 + w * 16 + quad * 4 + r;
#pragma unroll
        for (int dt = 0; dt < 8; dt++) {
            const int d = h * HD + dt * 16 + qm;
            O[(size_t)qg * DM + d] = f2b(o[dt][r] * inv);
        }
    }
}

// ---------------------------------------------------------------------------
extern "C" void kernel_launch(void* const* d_in, const int* in_sizes, int n_in,
                              void* d_out, int out_size, void* d_ws, size_t ws_size,
                              hipStream_t stream) {
    const int* isc = (const int*)d_in[9];

    int* flag = (int*)d_ws;
    u16* base = (u16*)((char*)d_ws + 256);

    const int NX = SEQ * DM;       // 8388608
    const int NW = DM * DM;        // 4194304
    const int NB = DM;

    // ws layout (u16 elems from base):
    unsigned long long off = 0;
    const unsigned long long oXc   = off; off += NX;
    const unsigned long long oWall = off; off += 3ull * NW;  // Wq,Wk,Wv
    const unsigned long long oWo   = off; off += NW;
    const unsigned long long oBall = off; off += 3ull * NB;  // bq,bk,bv
    const unsigned long long oBo   = off; off += NB;
    const unsigned long long oQ    = off; off += NX;
    const unsigned long long oK    = off; off += NX;
    const unsigned long long oVt   = off; off += NX;
    const unsigned long long oA    = off; off += NX;

    detect_dtype<<<1, 256, 0, stream>>>((const u16*)d_in[0], flag);

    ConvArgs ca;
    const unsigned long long dsts[9] = {oXc, oWall, oBall, oWall + NW, oBall + NB,
                                        oWall + 2ull * NW, oBall + 2ull * NB, oWo, oBo};
    for (int i = 0; i < 9; i++) {
        ca.src[i] = d_in[i];
        ca.dstoff[i] = dsts[i];
        ca.n[i] = in_sizes[i];
    }
    convert_all<<<dim3(NX / 8 / 256, 9), 256, 0, stream>>>(ca, base, flag);

    gemm_qkv<<<dim3(3 * DM / 192, SEQ / 256), 512, 0, stream>>>(
        base + oXc, base + oWall, base + oBall,
        base + oQ, base + oK, base + oVt);

    attn_kernel<<<dim3(SEQ / 128, NH), 512, 0, stream>>>(
        base + oQ, base + oK, base + oVt, base + oA, isc);

    gemm_out<<<dim3(DM / 128, SEQ / 256), 512, 0, stream>>>(
        base + oA, base + oWo, base + oBo, d_out, flag);
}